// Round 3
// baseline (44.222 us; speedup 1.0000x reference)
//
#include <hip/hip_runtime.h>
#include <hip/hip_bf16.h>

// Row-wise L2 normalization: x[i,:] / max(||x[i,:]||_2, guarded at 0 -> 1)
// Rows are 4 f32 -> exactly one 16B vector per row. Pure streaming,
// memory-bound. One thread per row (grid-strided): 16B load, 3 FMA, rsqrt,
// 4 mul, 16B NON-TEMPORAL store. Rationale: footprint = 128 MiB in +
// 128 MiB out = exactly the 256 MiB Infinity Cache; regular stores evict
// the input (rocprof: FETCH_SIZE = 64 MiB -> only half the input stayed
// L3-resident across replays). nt stores mark output lines evict-first.
//
// NOTE: __builtin_nontemporal_store requires a NATIVE vector type, not
// HIP_vector_type<float,4> (round-2 compile failure) -> use ext_vector_type.

typedef float f32x4 __attribute__((ext_vector_type(4)));

__global__ void __launch_bounds__(256)
l2norm_rows_kernel(const f32x4* __restrict__ x, f32x4* __restrict__ out, int nrows) {
    int stride = gridDim.x * blockDim.x;
    for (int i = blockIdx.x * blockDim.x + threadIdx.x; i < nrows; i += stride) {
        f32x4 v = x[i];
        float s = v.x * v.x + v.y * v.y + v.z * v.z + v.w * v.w;
        // zero-norm rows pass through unchanged (scale = 1)
        float inv = (s > 0.0f) ? rsqrtf(s) : 1.0f;
        f32x4 o = v * inv;
        __builtin_nontemporal_store(o, &out[i]);
    }
}

extern "C" void kernel_launch(void* const* d_in, const int* in_sizes, int n_in,
                              void* d_out, int out_size, void* d_ws, size_t ws_size,
                              hipStream_t stream) {
    const f32x4* x = (const f32x4*)d_in[0];
    f32x4* out = (f32x4*)d_out;
    int nrows = in_sizes[0] / 4;   // flat element count / 4 elems per row

    const int block = 256;
    int grid = (nrows + block - 1) / block;
    if (grid > 4096) grid = 4096;   // grid-stride the rest
    l2norm_rows_kernel<<<grid, block, 0, stream>>>(x, out, nrows);
}